// Round 1
// baseline (109.833 us; speedup 1.0000x reference)
//
#include <hip/hip_runtime.h>
#include <hip/hip_bf16.h>
#include <math.h>

// HGCN decoder, B=512, N=128, D=256, F=16, L=3, c=1 Poincare ball.
// One block per batch; T (node features, tangent space) lives in LDS across
// all 3 layers. FP16 MFMA (16x16x32), f32 accumulate. Threshold is 2% absmax.

typedef _Float16 f16;
typedef f16 f16x8 __attribute__((ext_vector_type(8)));
typedef f16 f16x4 __attribute__((ext_vector_type(4)));
typedef float f32x4 __attribute__((ext_vector_type(4)));

#define NB 512
#define NN 128
#define ND 256
#define NF 16
#define NL 3

#define EPSV   1e-7f
#define MAXN   0.99999f      // 1 - 1e-5
#define ATHMAX 6.1030340f    // atanh(1 - 1e-5)

// LDS tiles, XOR-swizzled in 16B (8-elem) chunks to kill stride-512B/256B
// bank conflicts on ds_read_b128 fragment loads (T2 swizzle).
__device__ __forceinline__ int sT_idx(int m, int k) {  // sT[128][256]
    return m * ND + ((((k >> 3) ^ (m & 7)) << 3) | (k & 7));
}
__device__ __forceinline__ int sV_idx(int n, int j) {  // sV[256][128]
    return n * NN + ((((j >> 3) ^ (n & 7)) << 3) | (j & 7));
}

// One-time: Wt[l][n][k] = W[l][k][n] (f16), WoutT[f][k] = Wout[k][f] (f16).
__global__ void prep_kernel(const float* __restrict__ Ws,
                            const float* __restrict__ Wout,
                            f16* __restrict__ Wt, f16* __restrict__ WoutT) {
    int idx = blockIdx.x * 256 + threadIdx.x;
    if (idx < NL * ND * ND) {
        int l = idx / (ND * ND);
        int r = idx % (ND * ND);
        int n = r >> 8;
        int k = r & 255;
        Wt[idx] = (f16)Ws[l * ND * ND + k * ND + n];
    }
    if (idx < NF * ND) {
        int f = idx >> 8;
        int k = idx & 255;
        WoutT[idx] = (f16)Wout[k * NF + f];
    }
}

__global__ __launch_bounds__(512, 1)
void hgcn_kernel(const float* __restrict__ x,
                 const float* __restrict__ adj,
                 const float* __restrict__ node_mask,
                 const f16*  __restrict__ Wt,
                 const float* __restrict__ bs,
                 const f16*  __restrict__ WoutT,
                 const float* __restrict__ bout,
                 float* __restrict__ out) {
    __shared__ __align__(16) f16 sT[NN * ND];  // [node m][feat k]  64KB
    __shared__ __align__(16) f16 sV[ND * NN];  // [feat n][node j]  64KB

    const int b    = blockIdx.x;
    const int tid  = threadIdx.x;
    const int wave = tid >> 6;   // 0..7
    const int lane = tid & 63;
    const int lg   = lane >> 4;  // 0..3
    const int lc   = lane & 15;

    const f32x4 fzero = {0.f, 0.f, 0.f, 0.f};

    // ---------- init: sT = f16(logmap0(proj(x[b]))) ----------
    {
        const float4* xb = (const float4*)(x + (size_t)b * NN * ND);
        for (int r = 0; r < 16; ++r) {
            int row = wave * 16 + r;
            float4 v = xb[row * 64 + lane];
            float ss = v.x * v.x + v.y * v.y + v.z * v.z + v.w * v.w;
            #pragma unroll
            for (int d = 1; d < 64; d <<= 1) ss += __shfl_xor(ss, d);
            float norm = sqrtf(ss);
            float n1  = fmaxf(norm, EPSV);
            float sc1 = (n1 > MAXN) ? (MAXN / n1) : 1.0f;   // proj
            float hn  = norm * sc1;
            float n2  = fmaxf(hn, EPSV);
            float aa  = fminf(n2, MAXN);
            float s   = sc1 * (atanhf(aa) / n2);            // logmap0
            f16x4 t4;
            t4[0] = (f16)(v.x * s); t4[1] = (f16)(v.y * s);
            t4[2] = (f16)(v.z * s); t4[3] = (f16)(v.w * s);
            int k0 = lane * 4;
            *(f16x4*)&sT[sT_idx(row, k0)] = t4;
        }
    }
    __syncthreads();

    const float* adjb = adj + (size_t)b * NN * NN;

    for (int layer = 0; layer < NL; ++layer) {
        // ---------- GEMM-a: sV[n][m] = (T @ W[l] + b[l])^T  (C^T = W^T T^T)
        // A-frags from global Wt[n][k] (contig k), B-frags from sT (contig k).
        const f16* WtL = Wt + layer * ND * ND;
        f32x4 acc_a[2][8];
        #pragma unroll
        for (int t = 0; t < 2; ++t)
            #pragma unroll
            for (int mt = 0; mt < 8; ++mt) acc_a[t][mt] = fzero;

        #pragma unroll
        for (int ks = 0; ks < 8; ++ks) {
            f16x8 afr[2];
            #pragma unroll
            for (int t = 0; t < 2; ++t) {
                int n = (wave * 2 + t) * 16 + lc;            // A row = lane&15
                afr[t] = *(const f16x8*)(WtL + n * ND + ks * 32 + lg * 8);
            }
            #pragma unroll
            for (int mt = 0; mt < 8; ++mt) {
                int m = mt * 16 + lc;                        // B col = lane&15
                f16x8 bfr = *(const f16x8*)&sT[sT_idx(m, ks * 32 + lg * 8)];
                acc_a[0][mt] = __builtin_amdgcn_mfma_f32_16x16x32_f16(afr[0], bfr, acc_a[0][mt], 0, 0, 0);
                acc_a[1][mt] = __builtin_amdgcn_mfma_f32_16x16x32_f16(afr[1], bfr, acc_a[1][mt], 0, 0, 0);
            }
        }
        // epilogue-a: + bias, cvt f16, store transposed into sV[n][m]
        #pragma unroll
        for (int t = 0; t < 2; ++t) {
            #pragma unroll
            for (int reg = 0; reg < 4; ++reg) {
                int n = (wave * 2 + t) * 16 + lg * 4 + reg;  // D row = n
                float bias = bs[layer * ND + n];
                #pragma unroll
                for (int mt = 0; mt < 8; ++mt) {
                    int m = mt * 16 + lc;                    // D col = m
                    sV[sV_idx(n, m)] = (f16)(acc_a[t][mt][reg] + bias);
                }
            }
        }
        __syncthreads();

        // ---------- GEMM-b: U[i][n] = adj[b] @ V ; wave owns rows i=wave*16..+15
        f32x4 acc_b[16];
        #pragma unroll
        for (int nt = 0; nt < 16; ++nt) acc_b[nt] = fzero;

        #pragma unroll
        for (int ks = 0; ks < 4; ++ks) {
            // A-frag straight from global adj (L2-resident), cvt f32->f16
            const float4* ap = (const float4*)(adjb + (wave * 16 + lc) * NN + ks * 32 + lg * 8);
            float4 alo = ap[0], ahi = ap[1];
            f16x8 afr;
            afr[0] = (f16)alo.x; afr[1] = (f16)alo.y; afr[2] = (f16)alo.z; afr[3] = (f16)alo.w;
            afr[4] = (f16)ahi.x; afr[5] = (f16)ahi.y; afr[6] = (f16)ahi.z; afr[7] = (f16)ahi.w;
            #pragma unroll
            for (int nt = 0; nt < 16; ++nt) {
                f16x8 bfr = *(const f16x8*)&sV[sV_idx(nt * 16 + lc, ks * 32 + lg * 8)];
                acc_b[nt] = __builtin_amdgcn_mfma_f32_16x16x32_f16(afr, bfr, acc_b[nt], 0, 0, 0);
            }
        }

        // epilogue-b: relu, row norm (16-lane butterfly), fused
        // logmap0(proj(expmap0(u))) = u * min(1, ATHMAX/||u||), write sT.
        float ss[4] = {0.f, 0.f, 0.f, 0.f};
        #pragma unroll
        for (int nt = 0; nt < 16; ++nt)
            #pragma unroll
            for (int reg = 0; reg < 4; ++reg) {
                float v = fmaxf(acc_b[nt][reg], 0.0f);
                acc_b[nt][reg] = v;
                ss[reg] += v * v;
            }
        #pragma unroll
        for (int d = 1; d < 16; d <<= 1)
            #pragma unroll
            for (int reg = 0; reg < 4; ++reg) ss[reg] += __shfl_xor(ss[reg], d);

        float scale[4];
        #pragma unroll
        for (int reg = 0; reg < 4; ++reg) {
            float nu = sqrtf(ss[reg]);
            scale[reg] = (nu > ATHMAX) ? (ATHMAX / nu) : 1.0f;
        }
        #pragma unroll
        for (int nt = 0; nt < 16; ++nt)
            #pragma unroll
            for (int reg = 0; reg < 4; ++reg) {
                int i = wave * 16 + lg * 4 + reg;            // D row = i
                int n = nt * 16 + lc;                        // D col = n
                sT[sT_idx(i, n)] = (f16)(acc_b[nt][reg] * scale[reg]);
            }
        __syncthreads();
    }

    // ---------- head: out = (out_tan @ Wout + bout) * node_mask ----------
    {
        f32x4 acc = fzero;
        #pragma unroll
        for (int ks = 0; ks < 8; ++ks) {
            f16x8 afr = *(const f16x8*)&sT[sT_idx(wave * 16 + lc, ks * 32 + lg * 8)];
            f16x8 bfr = *(const f16x8*)(WoutT + lc * ND + ks * 32 + lg * 8);
            acc = __builtin_amdgcn_mfma_f32_16x16x32_f16(afr, bfr, acc, 0, 0, 0);
        }
        #pragma unroll
        for (int reg = 0; reg < 4; ++reg) {
            int row = wave * 16 + lg * 4 + reg;
            float mask = node_mask[b * NN + row];
            out[((size_t)b * NN + row) * NF + lc] = (acc[reg] + bout[lc]) * mask;
        }
    }
}

extern "C" void kernel_launch(void* const* d_in, const int* in_sizes, int n_in,
                              void* d_out, int out_size, void* d_ws, size_t ws_size,
                              hipStream_t stream) {
    const float* x    = (const float*)d_in[0];
    const float* adj  = (const float*)d_in[1];
    const float* mask = (const float*)d_in[2];
    const float* Ws   = (const float*)d_in[3];
    const float* bsp  = (const float*)d_in[4];
    const float* Wout = (const float*)d_in[5];
    const float* bout = (const float*)d_in[6];

    f16* Wt    = (f16*)d_ws;                       // 3*256*256 f16 = 384KB
    f16* WoutT = Wt + NL * ND * ND;                // 16*256 f16 = 8KB

    prep_kernel<<<768, 256, 0, stream>>>(Ws, Wout, Wt, WoutT);
    hgcn_kernel<<<NB, 512, 0, stream>>>(x, adj, mask, Wt, bsp, WoutT, bout,
                                        (float*)d_out);
}